// Round 10
// baseline (1914.291 us; speedup 1.0000x reference)
//
#include <hip/hip_runtime.h>

// RNN_SingleOutput: 2-layer Elman ReLU RNN, B=256 T=512 I=64 H=256, fp32.
// Round-10 = round-9 (MFMA pivot, numerically validated: absmax 1.95e-3)
//            + the ONE fix: __syncthreads() in k_gemm1 between the block-wide
//            A-fragment loads and the in-place stores. R9's replay divergence
//            (+-1e36) was waves overwriting slot data other waves hadn't read
//            yet - a block-wide hazard my thread-local "data dependency"
//            argument missed.
//
// Why MFMA: R1-R7 proved the allocator won't keep >=128 weight floats/thread
// in arch VGPRs for VALU FMA (remat-reload or AGPR-park + accvgpr_read/use).
// MFMA reads AGPR operands natively -> parking is free. fp32 precision via
// bf16-split: W ~ Whi+Wlo, h ~ hhi+hlo, D += Whi*hhi + Whi*hlo + Wlo*hhi in
// fp32 accum (err ~2^-17; threshold 1.2e-2).
//
// Pipeline over ONE 128MiB ws buffer of 16KB slots [bc=16][t=512]:
//  1. k_gemm0: slot(bc,t) = pre0T[n][m] = x@Wih0^T + b  (fp32 [256n][16m])
//  2. k_rnn<WRITE_H1>: L0; consumes slot(bc,t) as C; writes h1 hi/lo bf16
//     planes [2][16m][256n] in-place over the same slot.
//  3. k_gemm1: reads h1 planes, writes pre1T fp32 in-place (same slot).
//  4. k_rnn<FC>: L1; consumes slot; fused FC head -> out[b*T+t].
//
// MFMA 16x16x32_bf16 layouts (m89-verified D; A/B k-permutation-invariant
// since A and B use the identical (lane,elem)->k formula):
//  A: row=lane&15, k=ks*32+8*(lane>>4)+j   B: col=lane&15, same k formula
//  D: col=lane&15, row=4*(lane>>4)+reg_j

#define T_ 512
#define H_ 256

typedef __attribute__((ext_vector_type(8))) short short8;
typedef __attribute__((ext_vector_type(4))) float f32x4;

#define MFMA(a, b, c) __builtin_amdgcn_mfma_f32_16x16x32_bf16(a, b, c, 0, 0, 0)

__device__ __forceinline__ unsigned short bf16rne(float f) {
    unsigned u = __float_as_uint(f);
    u += 0x7fff + ((u >> 16) & 1);
    return (unsigned short)(u >> 16);
}

// split 8 consecutive f32 (two float4) into hi/lo bf16 fragments
__device__ __forceinline__ void split8(const float4 a0, const float4 a1,
                                       short8& hi, short8& lo) {
    const float v[8] = {a0.x, a0.y, a0.z, a0.w, a1.x, a1.y, a1.z, a1.w};
#pragma unroll
    for (int j = 0; j < 8; ++j) {
        unsigned short hb = bf16rne(v[j]);
        float hf = __uint_as_float(((unsigned)hb) << 16);
        unsigned short lb = bf16rne(v[j] - hf);
        hi[j] = (short)hb;
        lo[j] = (short)lb;
    }
}

// ---------------------------------------------------------- gemm0 (K=64) ---
// slot(bc,t)[n][m] = x[bc*16+m][t][:] @ Wih0[n][:] + bih0[n] + bhh0[n]
__global__ __launch_bounds__(256) void k_gemm0(
    const float* __restrict__ x, const float* __restrict__ Wih,
    const float* __restrict__ bih, const float* __restrict__ bhh,
    float* __restrict__ buf)
{
    const int tid = threadIdx.x, lane = tid & 63, wv = tid >> 6;
    const int l15 = lane & 15, lg = lane >> 4;
    const int bc = blockIdx.x & 15;
    const int t0 = (blockIdx.x >> 4) * 32;

    short8 bhi[4][2], blo[4][2];
    f32x4 bias[4];
#pragma unroll
    for (int nt = 0; nt < 4; ++nt) {
        const int n = wv * 64 + nt * 16 + l15;
#pragma unroll
        for (int ks = 0; ks < 2; ++ks) {
            const float4* p = (const float4*)(Wih + (size_t)n * 64 + ks * 32 + 8 * lg);
            split8(p[0], p[1], bhi[nt][ks], blo[nt][ks]);
        }
        const float b = bih[n] + bhh[n];
        bias[nt] = f32x4{b, b, b, b};
    }
#pragma unroll 1
    for (int t = t0; t < t0 + 32; ++t) {
        short8 ahi[2], alo[2];
#pragma unroll
        for (int ks = 0; ks < 2; ++ks) {
            const float4* p =
                (const float4*)(x + ((size_t)(bc * 16 + l15) * T_ + t) * 64 + ks * 32 + 8 * lg);
            split8(p[0], p[1], ahi[ks], alo[ks]);
        }
        f32x4 acc[4];
#pragma unroll
        for (int nt = 0; nt < 4; ++nt) acc[nt] = bias[nt];
#pragma unroll
        for (int ks = 0; ks < 2; ++ks) {
#pragma unroll
            for (int nt = 0; nt < 4; ++nt) acc[nt] = MFMA(ahi[ks], bhi[nt][ks], acc[nt]);
#pragma unroll
            for (int nt = 0; nt < 4; ++nt) acc[nt] = MFMA(alo[ks], bhi[nt][ks], acc[nt]);
#pragma unroll
            for (int nt = 0; nt < 4; ++nt) acc[nt] = MFMA(ahi[ks], blo[nt][ks], acc[nt]);
        }
        float* slot = buf + ((size_t)bc * T_ + t) * 4096;
#pragma unroll
        for (int nt = 0; nt < 4; ++nt)
            *(f32x4*)(slot + (wv * 64 + nt * 16 + l15) * 16 + 4 * lg) = acc[nt];
    }
}

// --------------------------------------------------------- gemm1 (K=256) ---
// slot holds h1 planes [2][16m][256n] bf16; overwrite with pre1T fp32 [n][m].
// RACE FIX (R9): __syncthreads() between block-wide A loads and in-place
// stores. Each (bc,t) slot is exclusive to this block; t-iters touch
// disjoint slots, so the single barrier per t fully orders read->write.
__global__ __launch_bounds__(256, 1) void k_gemm1(
    const float* __restrict__ Wih, const float* __restrict__ bih,
    const float* __restrict__ bhh, float* __restrict__ buf)
{
    const int tid = threadIdx.x, lane = tid & 63, wv = tid >> 6;
    const int l15 = lane & 15, lg = lane >> 4;
    const int bc = blockIdx.x & 15;
    const int t0 = (blockIdx.x >> 4) * 32;

    short8 bhi[4][8], blo[4][8];
    f32x4 bias[4];
#pragma unroll
    for (int nt = 0; nt < 4; ++nt) {
        const int n = wv * 64 + nt * 16 + l15;
#pragma unroll
        for (int ks = 0; ks < 8; ++ks) {
            const float4* p = (const float4*)(Wih + (size_t)n * H_ + ks * 32 + 8 * lg);
            split8(p[0], p[1], bhi[nt][ks], blo[nt][ks]);
        }
        const float b = bih[n] + bhh[n];
        bias[nt] = f32x4{b, b, b, b};
    }
#pragma unroll 1
    for (int t = t0; t < t0 + 32; ++t) {
        float* slot = buf + ((size_t)bc * T_ + t) * 4096;
        const unsigned short* g = (const unsigned short*)slot;
        short8 ahi[8], alo[8];
#pragma unroll
        for (int ks = 0; ks < 8; ++ks) {
            ahi[ks] = *(const short8*)(g + (size_t)l15 * H_ + ks * 32 + 8 * lg);
            alo[ks] = *(const short8*)(g + 4096 + (size_t)l15 * H_ + ks * 32 + 8 * lg);
        }
        __syncthreads();   // ALL waves' A loads complete before ANY store below
        f32x4 acc[4];
#pragma unroll
        for (int nt = 0; nt < 4; ++nt) acc[nt] = bias[nt];
#pragma unroll
        for (int ks = 0; ks < 8; ++ks) {
#pragma unroll
            for (int nt = 0; nt < 4; ++nt) acc[nt] = MFMA(ahi[ks], bhi[nt][ks], acc[nt]);
#pragma unroll
            for (int nt = 0; nt < 4; ++nt) acc[nt] = MFMA(alo[ks], bhi[nt][ks], acc[nt]);
#pragma unroll
            for (int nt = 0; nt < 4; ++nt) acc[nt] = MFMA(ahi[ks], blo[nt][ks], acc[nt]);
        }
#pragma unroll
        for (int nt = 0; nt < 4; ++nt)
            *(f32x4*)(slot + (wv * 64 + nt * 16 + l15) * 16 + 4 * lg) = acc[nt];
    }
}

// ------------------------------------------------------------- recurrence ---
template <bool WRITE_H1, bool FC>
__global__ __launch_bounds__(256, 1) void k_rnn(
    float* __restrict__ buf, const float* __restrict__ Whh,
    const float* __restrict__ Wfc, const float* __restrict__ bfcp,
    float* __restrict__ out)
{
    const int tid = threadIdx.x, lane = tid & 63, wv = tid >> 6;
    const int l15 = lane & 15, lg = lane >> 4;
    const int bc = blockIdx.x;

    // B-fragments of W_hh: parked wherever the allocator likes (VGPR or
    // AGPR) - MFMA reads both natively, so parking costs nothing.
    short8 bhi[4][8], blo[4][8];
#pragma unroll
    for (int nt = 0; nt < 4; ++nt) {
        const int n = wv * 64 + nt * 16 + l15;
#pragma unroll
        for (int ks = 0; ks < 8; ++ks) {
            const float4* p = (const float4*)(Whh + (size_t)n * H_ + ks * 32 + 8 * lg);
            split8(p[0], p[1], bhi[nt][ks], blo[nt][ks]);
        }
    }
    float wfc4[4];
    float bfc = 0.f;
    if (FC) {
#pragma unroll
        for (int nt = 0; nt < 4; ++nt) wfc4[nt] = Wfc[wv * 64 + nt * 16 + l15];
        bfc = bfcp[0];
    }

    __shared__ unsigned short hb[2][2][16][264];  // [dbuf][plane][m][k], +8 pad
    __shared__ float wavesum[2][4][16];

    for (int i = tid; i < (int)(sizeof(hb) / 16); i += 256)
        ((uint4*)hb)[i] = make_uint4(0u, 0u, 0u, 0u);
    __syncthreads();

    float* slot0 = buf + (size_t)bc * T_ * 4096;
    f32x4 cfrag[4];
#pragma unroll
    for (int nt = 0; nt < 4; ++nt)
        cfrag[nt] = *(const f32x4*)(slot0 + (wv * 64 + nt * 16 + l15) * 16 + 4 * lg);

    int p = 0;
#pragma unroll 1
    for (int t = 0; t < T_; ++t) {
        short8 ahi[8], alo[8];
#pragma unroll
        for (int ks = 0; ks < 8; ++ks) {
            ahi[ks] = *(const short8*)&hb[p][0][l15][ks * 32 + 8 * lg];
            alo[ks] = *(const short8*)&hb[p][1][l15][ks * 32 + 8 * lg];
        }
        f32x4 acc[4];
#pragma unroll
        for (int nt = 0; nt < 4; ++nt) acc[nt] = cfrag[nt];
#pragma unroll
        for (int ks = 0; ks < 8; ++ks) {
#pragma unroll
            for (int nt = 0; nt < 4; ++nt) acc[nt] = MFMA(ahi[ks], bhi[nt][ks], acc[nt]);
#pragma unroll
            for (int nt = 0; nt < 4; ++nt) acc[nt] = MFMA(alo[ks], bhi[nt][ks], acc[nt]);
#pragma unroll
            for (int nt = 0; nt < 4; ++nt) acc[nt] = MFMA(ahi[ks], blo[nt][ks], acc[nt]);
        }
        if (t + 1 < T_) {  // prefetch next step's C (pre) tile
#pragma unroll
            for (int nt = 0; nt < 4; ++nt)
                cfrag[nt] = *(const f32x4*)(slot0 + (size_t)(t + 1) * 4096 +
                                            (wv * 64 + nt * 16 + l15) * 16 + 4 * lg);
        }
        // epilogue: relu, bf16-split state update, optional FC partial
        float fcp[4] = {0.f, 0.f, 0.f, 0.f};
#pragma unroll
        for (int nt = 0; nt < 4; ++nt) {
            const int n = wv * 64 + nt * 16 + l15;
#pragma unroll
            for (int j = 0; j < 4; ++j) {
                float v = fmaxf(acc[nt][j], 0.f);
                unsigned short hv = bf16rne(v);
                float hf = __uint_as_float(((unsigned)hv) << 16);
                unsigned short lv = bf16rne(v - hf);
                hb[p ^ 1][0][4 * lg + j][n] = hv;
                hb[p ^ 1][1][4 * lg + j][n] = lv;
                if (FC) fcp[j] = fmaf(v, wfc4[nt], fcp[j]);
            }
        }
        if (FC) {
#pragma unroll
            for (int j = 0; j < 4; ++j) {
                float f = fcp[j];
                f += __shfl_xor(f, 1, 64);
                f += __shfl_xor(f, 2, 64);
                f += __shfl_xor(f, 4, 64);
                f += __shfl_xor(f, 8, 64);
                fcp[j] = f;
            }
            if (l15 == 0) {
#pragma unroll
                for (int j = 0; j < 4; ++j) wavesum[p][wv][4 * lg + j] = fcp[j];
            }
        }
        __syncthreads();
        if (WRITE_H1) {  // copy new h planes -> global slot(bc,t) (overwrites pre0T)
            unsigned short* g = (unsigned short*)(slot0 + (size_t)t * 4096);
            const int r = tid >> 4, c = (tid & 15) * 16;
#pragma unroll
            for (int pl = 0; pl < 2; ++pl) {
                uint4 v0 = *(const uint4*)&hb[p ^ 1][pl][r][c];
                uint4 v1 = *(const uint4*)&hb[p ^ 1][pl][r][c + 8];
                *(uint4*)(g + pl * 4096 + r * H_ + c) = v0;
                *(uint4*)(g + pl * 4096 + r * H_ + c + 8) = v1;
            }
        }
        if (FC) {
            if (wv == 0 && lane < 16) {
                float s = wavesum[p][0][lane] + wavesum[p][1][lane] +
                          wavesum[p][2][lane] + wavesum[p][3][lane] + bfc;
                out[(size_t)(bc * 16 + lane) * T_ + t] = s;
            }
        }
        p ^= 1;
    }
}

extern "C" void kernel_launch(void* const* d_in, const int* in_sizes, int n_in,
                              void* d_out, int out_size, void* d_ws, size_t ws_size,
                              hipStream_t stream) {
    (void)in_sizes; (void)n_in; (void)out_size; (void)ws_size;
    const float* x    = (const float*)d_in[0];
    const float* Wih0 = (const float*)d_in[1];
    const float* Whh0 = (const float*)d_in[2];
    const float* bih0 = (const float*)d_in[3];
    const float* bhh0 = (const float*)d_in[4];
    const float* Wih1 = (const float*)d_in[5];
    const float* Whh1 = (const float*)d_in[6];
    const float* bih1 = (const float*)d_in[7];
    const float* bhh1 = (const float*)d_in[8];
    const float* Wfc  = (const float*)d_in[9];
    const float* bfc  = (const float*)d_in[10];

    float* buf = (float*)d_ws;  // 16KB x 16 x 512 slots = 128 MiB
    float* out = (float*)d_out;

    k_gemm0<<<dim3(256), dim3(256), 0, stream>>>(x, Wih0, bih0, bhh0, buf);
    k_rnn<true, false><<<dim3(16), dim3(256), 0, stream>>>(buf, Whh0, Wfc, bfc, out);
    k_gemm1<<<dim3(256), dim3(256), 0, stream>>>(Wih1, bih1, bhh1, buf);
    k_rnn<false, true><<<dim3(16), dim3(256), 0, stream>>>(buf, Whh1, Wfc, bfc, out);
}

// Round 11
// 1835.387 us; speedup vs baseline: 1.0430x; 1.0430x over previous
//
#include <hip/hip_runtime.h>

// RNN_SingleOutput: 2-layer Elman ReLU RNN, B=256 T=512 I=64 H=256, fp32.
// Round-11 = round-10 (MFMA pivot, validated absmax 1.95e-3) + latency fixes:
//  R10 counters: k_rnn 935us each, MfmaUtil 2.2%, VALUBusy 1.9%, Occ 0.75%
//  -> pure latency-bound: 64 waves on-chip, 1 wave/SIMD, and the cfrag
//  prefetch (issued AFTER the MFMAs) is drained by the compiler's
//  s_waitcnt vmcnt(0)-before-s_barrier with no covering work (~900cy/step).
//  Fix 1: k_rnn at 512 threads -> 8 waves, 2/SIMD; per-wave work halves
//         (2 output tiles, 48 MFMAs); co-resident waves hide dep latency.
//         B-frags may park in AGPRs - free, MFMA reads AGPRs natively.
//  Fix 2: cfrag(t+1) global loads issued at loop TOP -> ~1000cy of step work
//         covers the HBM latency before the barrier drain.
// Pipeline over ONE 128MiB ws buffer of 16KB slots [bc=16][t=512]:
//  1. k_gemm0: slot(bc,t) = pre0T[n][m] = x@Wih0^T + b   (fp32 [256n][16m])
//  2. k_rnn<WRITE_H1>: L0; consumes slot as C; writes h1 hi/lo bf16 planes
//     [2][16m][256n] in-place.
//  3. k_gemm1: h1 planes -> pre1T fp32 in-place (barrier between block-wide
//     loads and in-place stores - R9's race).
//  4. k_rnn<FC>: L1 + fused FC head -> out.
// bf16-split: D += Whi*hhi + Whi*hlo + Wlo*hhi, fp32 accum (err ~2^-17).

#define T_ 512
#define H_ 256

typedef __attribute__((ext_vector_type(8))) short short8;
typedef __attribute__((ext_vector_type(4))) float f32x4;

#define MFMA(a, b, c) __builtin_amdgcn_mfma_f32_16x16x32_bf16(a, b, c, 0, 0, 0)

__device__ __forceinline__ unsigned short bf16rne(float f) {
    unsigned u = __float_as_uint(f);
    u += 0x7fff + ((u >> 16) & 1);
    return (unsigned short)(u >> 16);
}

__device__ __forceinline__ void split8(const float4 a0, const float4 a1,
                                       short8& hi, short8& lo) {
    const float v[8] = {a0.x, a0.y, a0.z, a0.w, a1.x, a1.y, a1.z, a1.w};
#pragma unroll
    for (int j = 0; j < 8; ++j) {
        unsigned short hb = bf16rne(v[j]);
        float hf = __uint_as_float(((unsigned)hb) << 16);
        unsigned short lb = bf16rne(v[j] - hf);
        hi[j] = (short)hb;
        lo[j] = (short)lb;
    }
}

// ---------------------------------------------------------- gemm0 (K=64) ---
__global__ __launch_bounds__(256) void k_gemm0(
    const float* __restrict__ x, const float* __restrict__ Wih,
    const float* __restrict__ bih, const float* __restrict__ bhh,
    float* __restrict__ buf)
{
    const int tid = threadIdx.x, lane = tid & 63, wv = tid >> 6;
    const int l15 = lane & 15, lg = lane >> 4;
    const int bc = blockIdx.x & 15;
    const int t0 = (blockIdx.x >> 4) * 32;

    short8 bhi[4][2], blo[4][2];
    f32x4 bias[4];
#pragma unroll
    for (int nt = 0; nt < 4; ++nt) {
        const int n = wv * 64 + nt * 16 + l15;
#pragma unroll
        for (int ks = 0; ks < 2; ++ks) {
            const float4* p = (const float4*)(Wih + (size_t)n * 64 + ks * 32 + 8 * lg);
            split8(p[0], p[1], bhi[nt][ks], blo[nt][ks]);
        }
        const float b = bih[n] + bhh[n];
        bias[nt] = f32x4{b, b, b, b};
    }
#pragma unroll 1
    for (int t = t0; t < t0 + 32; ++t) {
        short8 ahi[2], alo[2];
#pragma unroll
        for (int ks = 0; ks < 2; ++ks) {
            const float4* p =
                (const float4*)(x + ((size_t)(bc * 16 + l15) * T_ + t) * 64 + ks * 32 + 8 * lg);
            split8(p[0], p[1], ahi[ks], alo[ks]);
        }
        f32x4 acc[4];
#pragma unroll
        for (int nt = 0; nt < 4; ++nt) acc[nt] = bias[nt];
#pragma unroll
        for (int ks = 0; ks < 2; ++ks) {
#pragma unroll
            for (int nt = 0; nt < 4; ++nt) acc[nt] = MFMA(ahi[ks], bhi[nt][ks], acc[nt]);
#pragma unroll
            for (int nt = 0; nt < 4; ++nt) acc[nt] = MFMA(alo[ks], bhi[nt][ks], acc[nt]);
#pragma unroll
            for (int nt = 0; nt < 4; ++nt) acc[nt] = MFMA(ahi[ks], blo[nt][ks], acc[nt]);
        }
        float* slot = buf + ((size_t)bc * T_ + t) * 4096;
#pragma unroll
        for (int nt = 0; nt < 4; ++nt)
            *(f32x4*)(slot + (wv * 64 + nt * 16 + l15) * 16 + 4 * lg) = acc[nt];
    }
}

// --------------------------------------------------------- gemm1 (K=256) ---
__global__ __launch_bounds__(256, 1) void k_gemm1(
    const float* __restrict__ Wih, const float* __restrict__ bih,
    const float* __restrict__ bhh, float* __restrict__ buf)
{
    const int tid = threadIdx.x, lane = tid & 63, wv = tid >> 6;
    const int l15 = lane & 15, lg = lane >> 4;
    const int bc = blockIdx.x & 15;
    const int t0 = (blockIdx.x >> 4) * 32;

    short8 bhi[4][8], blo[4][8];
    f32x4 bias[4];
#pragma unroll
    for (int nt = 0; nt < 4; ++nt) {
        const int n = wv * 64 + nt * 16 + l15;
#pragma unroll
        for (int ks = 0; ks < 8; ++ks) {
            const float4* p = (const float4*)(Wih + (size_t)n * H_ + ks * 32 + 8 * lg);
            split8(p[0], p[1], bhi[nt][ks], blo[nt][ks]);
        }
        const float b = bih[n] + bhh[n];
        bias[nt] = f32x4{b, b, b, b};
    }
#pragma unroll 1
    for (int t = t0; t < t0 + 32; ++t) {
        float* slot = buf + ((size_t)bc * T_ + t) * 4096;
        const unsigned short* g = (const unsigned short*)slot;
        short8 ahi[8], alo[8];
#pragma unroll
        for (int ks = 0; ks < 8; ++ks) {
            ahi[ks] = *(const short8*)(g + (size_t)l15 * H_ + ks * 32 + 8 * lg);
            alo[ks] = *(const short8*)(g + 4096 + (size_t)l15 * H_ + ks * 32 + 8 * lg);
        }
        __syncthreads();   // ALL waves' loads complete before ANY in-place store
        f32x4 acc[4];
#pragma unroll
        for (int nt = 0; nt < 4; ++nt) acc[nt] = bias[nt];
#pragma unroll
        for (int ks = 0; ks < 8; ++ks) {
#pragma unroll
            for (int nt = 0; nt < 4; ++nt) acc[nt] = MFMA(ahi[ks], bhi[nt][ks], acc[nt]);
#pragma unroll
            for (int nt = 0; nt < 4; ++nt) acc[nt] = MFMA(alo[ks], bhi[nt][ks], acc[nt]);
#pragma unroll
            for (int nt = 0; nt < 4; ++nt) acc[nt] = MFMA(ahi[ks], blo[nt][ks], acc[nt]);
        }
#pragma unroll
        for (int nt = 0; nt < 4; ++nt)
            *(f32x4*)(slot + (wv * 64 + nt * 16 + l15) * 16 + 4 * lg) = acc[nt];
    }
}

// ---------------------------------------------- recurrence: 512 thr, 8 wv ---
template <bool WRITE_H1, bool FC>
__global__ __launch_bounds__(512, 1) void k_rnn(
    float* __restrict__ buf, const float* __restrict__ Whh,
    const float* __restrict__ Wfc, const float* __restrict__ bfcp,
    float* __restrict__ out)
{
    const int tid = threadIdx.x, lane = tid & 63, wv = tid >> 6;  // wv 0..7
    const int l15 = lane & 15, lg = lane >> 4;
    const int bc = blockIdx.x;

    // each wave owns 32 output cols: n = wv*32 + nt*16 + l15, nt in {0,1}
    short8 bhi[2][8], blo[2][8];
#pragma unroll
    for (int nt = 0; nt < 2; ++nt) {
        const int n = wv * 32 + nt * 16 + l15;
#pragma unroll
        for (int ks = 0; ks < 8; ++ks) {
            const float4* p = (const float4*)(Whh + (size_t)n * H_ + ks * 32 + 8 * lg);
            split8(p[0], p[1], bhi[nt][ks], blo[nt][ks]);
        }
    }
    float wfc2[2];
    float bfc = 0.f;
    if (FC) {
#pragma unroll
        for (int nt = 0; nt < 2; ++nt) wfc2[nt] = Wfc[wv * 32 + nt * 16 + l15];
        bfc = bfcp[0];
    }

    __shared__ unsigned short hb[2][2][16][264];  // [dbuf][plane][m][k], +8 pad
    __shared__ float wavesum[2][8][16];

    for (int i = tid; i < (int)(sizeof(hb) / 16); i += 512)
        ((uint4*)hb)[i] = make_uint4(0u, 0u, 0u, 0u);
    __syncthreads();

    float* slot0 = buf + (size_t)bc * T_ * 4096;
    f32x4 cfrag[2];
#pragma unroll
    for (int nt = 0; nt < 2; ++nt)
        cfrag[nt] = *(const f32x4*)(slot0 + (wv * 32 + nt * 16 + l15) * 16 + 4 * lg);

    int p = 0;
#pragma unroll 1
    for (int t = 0; t < T_; ++t) {
        // prefetch t+1's C tile FIRST: full step of work covers HBM latency
        // before the pre-barrier vmcnt drain.
        f32x4 cnext[2];
        if (t + 1 < T_) {
#pragma unroll
            for (int nt = 0; nt < 2; ++nt)
                cnext[nt] = *(const f32x4*)(slot0 + (size_t)(t + 1) * 4096 +
                                            (wv * 32 + nt * 16 + l15) * 16 + 4 * lg);
        }
        short8 ahi[8], alo[8];
#pragma unroll
        for (int ks = 0; ks < 8; ++ks) {
            ahi[ks] = *(const short8*)&hb[p][0][l15][ks * 32 + 8 * lg];
            alo[ks] = *(const short8*)&hb[p][1][l15][ks * 32 + 8 * lg];
        }
        f32x4 acc[2];
#pragma unroll
        for (int nt = 0; nt < 2; ++nt) acc[nt] = cfrag[nt];
#pragma unroll
        for (int ks = 0; ks < 8; ++ks) {
#pragma unroll
            for (int nt = 0; nt < 2; ++nt) acc[nt] = MFMA(ahi[ks], bhi[nt][ks], acc[nt]);
#pragma unroll
            for (int nt = 0; nt < 2; ++nt) acc[nt] = MFMA(alo[ks], bhi[nt][ks], acc[nt]);
#pragma unroll
            for (int nt = 0; nt < 2; ++nt) acc[nt] = MFMA(ahi[ks], blo[nt][ks], acc[nt]);
        }
        // epilogue: relu, bf16-split state update, optional FC partial
        float fcp[4] = {0.f, 0.f, 0.f, 0.f};
#pragma unroll
        for (int nt = 0; nt < 2; ++nt) {
            const int n = wv * 32 + nt * 16 + l15;
#pragma unroll
            for (int j = 0; j < 4; ++j) {
                float v = fmaxf(acc[nt][j], 0.f);
                unsigned short hv = bf16rne(v);
                float hf = __uint_as_float(((unsigned)hv) << 16);
                unsigned short lv = bf16rne(v - hf);
                hb[p ^ 1][0][4 * lg + j][n] = hv;
                hb[p ^ 1][1][4 * lg + j][n] = lv;
                if (FC) fcp[j] = fmaf(v, wfc2[nt], fcp[j]);
            }
        }
        if (FC) {
#pragma unroll
            for (int j = 0; j < 4; ++j) {
                float f = fcp[j];
                f += __shfl_xor(f, 1, 64);
                f += __shfl_xor(f, 2, 64);
                f += __shfl_xor(f, 4, 64);
                f += __shfl_xor(f, 8, 64);
                fcp[j] = f;
            }
            if (l15 == 0) {
#pragma unroll
                for (int j = 0; j < 4; ++j) wavesum[p][wv][4 * lg + j] = fcp[j];
            }
        }
        __syncthreads();
        if (WRITE_H1) {  // copy new h planes -> global slot(bc,t)
            unsigned short* g = (unsigned short*)(slot0 + (size_t)t * 4096);
            const int pl = tid >> 8, rr = (tid >> 4) & 15, c = (tid & 15) * 16;
            uint4 v0 = *(const uint4*)&hb[p ^ 1][pl][rr][c];
            uint4 v1 = *(const uint4*)&hb[p ^ 1][pl][rr][c + 8];
            *(uint4*)(g + pl * 4096 + rr * H_ + c) = v0;
            *(uint4*)(g + pl * 4096 + rr * H_ + c + 8) = v1;
        }
        if (FC) {
            if (wv == 0 && lane < 16) {
                float s = bfc;
#pragma unroll
                for (int w8 = 0; w8 < 8; ++w8) s += wavesum[p][w8][lane];
                out[(size_t)(bc * 16 + lane) * T_ + t] = s;
            }
        }
#pragma unroll
        for (int nt = 0; nt < 2; ++nt) cfrag[nt] = cnext[nt];
        p ^= 1;
    }
}

extern "C" void kernel_launch(void* const* d_in, const int* in_sizes, int n_in,
                              void* d_out, int out_size, void* d_ws, size_t ws_size,
                              hipStream_t stream) {
    (void)in_sizes; (void)n_in; (void)out_size; (void)ws_size;
    const float* x    = (const float*)d_in[0];
    const float* Wih0 = (const float*)d_in[1];
    const float* Whh0 = (const float*)d_in[2];
    const float* bih0 = (const float*)d_in[3];
    const float* bhh0 = (const float*)d_in[4];
    const float* Wih1 = (const float*)d_in[5];
    const float* Whh1 = (const float*)d_in[6];
    const float* bih1 = (const float*)d_in[7];
    const float* bhh1 = (const float*)d_in[8];
    const float* Wfc  = (const float*)d_in[9];
    const float* bfc  = (const float*)d_in[10];

    float* buf = (float*)d_ws;  // 16KB x 16 x 512 slots = 128 MiB
    float* out = (float*)d_out;

    k_gemm0<<<dim3(256), dim3(256), 0, stream>>>(x, Wih0, bih0, bhh0, buf);
    k_rnn<true, false><<<dim3(16), dim3(512), 0, stream>>>(buf, Whh0, Wfc, bfc, out);
    k_gemm1<<<dim3(256), dim3(256), 0, stream>>>(Wih1, bih1, bhh1, buf);
    k_rnn<false, true><<<dim3(16), dim3(512), 0, stream>>>(buf, Whh1, Wfc, bfc, out);
}

// Round 12
// 1413.533 us; speedup vs baseline: 1.3543x; 1.2984x over previous
//
#include <hip/hip_runtime.h>

// RNN_SingleOutput: 2-layer Elman ReLU RNN, B=256 T=512 I=64 H=256, fp32.
// Round-12: SHRINK THE STATE. R11 counters (normalized to the 16 busy CUs:
// MfmaUtil 36%, VALUBusy 26%) + arithmetic showed the k_rnn step cost is LDS
// READ BW: every wave reads the full h state (hi+lo bf16, 16KB) as its MFMA
// A-operand -> 8 waves x 16KB = 128KB/step over a 128B/cy pipe = 1024cy floor
// (observed 4200 with conflicts/chains). N-split redundancy is structural, so
// halve the state instead: h is stored as bf16 HI ONLY. The W operand stays
// split (bhi+blo), so per-step error is only the dropped h-residual term:
// ~3e-4/step -> ~1.5e-3 in h -> predicted absmax 3-6e-3 vs threshold 12.3e-3.
//  - A-traffic 64KB/step (512cy floor); MFMAs 48->32/wave; epilogue halves.
// Pipeline over ONE 128MiB ws buffer of 16KB slots [bc=16][t=512]:
//  1. k_gemm0: slot(bc,t) = pre0T[n][m] fp32  (x@Wih0^T + b)
//  2. k_rnn<WRITE_H1>: L0; consumes slot as C; writes h1 bf16-hi [16m][256n]
//     in-place (8KB).
//  3. k_gemm1: h1-hi -> pre1T fp32 in-place (barrier between block-wide loads
//     and in-place stores - R9's race).
//  4. k_rnn<FC>: L1 + fused FC head -> out.

#define T_ 512
#define H_ 256

typedef __attribute__((ext_vector_type(8))) short short8;
typedef __attribute__((ext_vector_type(4))) float f32x4;

#define MFMA(a, b, c) __builtin_amdgcn_mfma_f32_16x16x32_bf16(a, b, c, 0, 0, 0)

__device__ __forceinline__ unsigned short bf16rne(float f) {
    unsigned u = __float_as_uint(f);
    u += 0x7fff + ((u >> 16) & 1);
    return (unsigned short)(u >> 16);
}

__device__ __forceinline__ void split8(const float4 a0, const float4 a1,
                                       short8& hi, short8& lo) {
    const float v[8] = {a0.x, a0.y, a0.z, a0.w, a1.x, a1.y, a1.z, a1.w};
#pragma unroll
    for (int j = 0; j < 8; ++j) {
        unsigned short hb = bf16rne(v[j]);
        float hf = __uint_as_float(((unsigned)hb) << 16);
        unsigned short lb = bf16rne(v[j] - hf);
        hi[j] = (short)hb;
        lo[j] = (short)lb;
    }
}

// ---------------------------------------------------------- gemm0 (K=64) ---
__global__ __launch_bounds__(256) void k_gemm0(
    const float* __restrict__ x, const float* __restrict__ Wih,
    const float* __restrict__ bih, const float* __restrict__ bhh,
    float* __restrict__ buf)
{
    const int tid = threadIdx.x, lane = tid & 63, wv = tid >> 6;
    const int l15 = lane & 15, lg = lane >> 4;
    const int bc = blockIdx.x & 15;
    const int t0 = (blockIdx.x >> 4) * 32;

    short8 bhi[4][2], blo[4][2];
    f32x4 bias[4];
#pragma unroll
    for (int nt = 0; nt < 4; ++nt) {
        const int n = wv * 64 + nt * 16 + l15;
#pragma unroll
        for (int ks = 0; ks < 2; ++ks) {
            const float4* p = (const float4*)(Wih + (size_t)n * 64 + ks * 32 + 8 * lg);
            split8(p[0], p[1], bhi[nt][ks], blo[nt][ks]);
        }
        const float b = bih[n] + bhh[n];
        bias[nt] = f32x4{b, b, b, b};
    }
#pragma unroll 1
    for (int t = t0; t < t0 + 32; ++t) {
        short8 ahi[2], alo[2];
#pragma unroll
        for (int ks = 0; ks < 2; ++ks) {
            const float4* p =
                (const float4*)(x + ((size_t)(bc * 16 + l15) * T_ + t) * 64 + ks * 32 + 8 * lg);
            split8(p[0], p[1], ahi[ks], alo[ks]);
        }
        f32x4 acc[4];
#pragma unroll
        for (int nt = 0; nt < 4; ++nt) acc[nt] = bias[nt];
#pragma unroll
        for (int ks = 0; ks < 2; ++ks) {
#pragma unroll
            for (int nt = 0; nt < 4; ++nt) acc[nt] = MFMA(ahi[ks], bhi[nt][ks], acc[nt]);
#pragma unroll
            for (int nt = 0; nt < 4; ++nt) acc[nt] = MFMA(alo[ks], bhi[nt][ks], acc[nt]);
#pragma unroll
            for (int nt = 0; nt < 4; ++nt) acc[nt] = MFMA(ahi[ks], blo[nt][ks], acc[nt]);
        }
        float* slot = buf + ((size_t)bc * T_ + t) * 4096;
#pragma unroll
        for (int nt = 0; nt < 4; ++nt)
            *(f32x4*)(slot + (wv * 64 + nt * 16 + l15) * 16 + 4 * lg) = acc[nt];
    }
}

// --------------------------------------------------- gemm1 (K=256, hi-A) ---
__global__ __launch_bounds__(256, 1) void k_gemm1(
    const float* __restrict__ Wih, const float* __restrict__ bih,
    const float* __restrict__ bhh, float* __restrict__ buf)
{
    const int tid = threadIdx.x, lane = tid & 63, wv = tid >> 6;
    const int l15 = lane & 15, lg = lane >> 4;
    const int bc = blockIdx.x & 15;
    const int t0 = (blockIdx.x >> 4) * 32;

    short8 bhi[4][8], blo[4][8];
    f32x4 bias[4];
#pragma unroll
    for (int nt = 0; nt < 4; ++nt) {
        const int n = wv * 64 + nt * 16 + l15;
#pragma unroll
        for (int ks = 0; ks < 8; ++ks) {
            const float4* p = (const float4*)(Wih + (size_t)n * H_ + ks * 32 + 8 * lg);
            split8(p[0], p[1], bhi[nt][ks], blo[nt][ks]);
        }
        const float b = bih[n] + bhh[n];
        bias[nt] = f32x4{b, b, b, b};
    }
#pragma unroll 1
    for (int t = t0; t < t0 + 32; ++t) {
        float* slot = buf + ((size_t)bc * T_ + t) * 4096;
        const unsigned short* g = (const unsigned short*)slot;
        short8 ahi[8];
#pragma unroll
        for (int ks = 0; ks < 8; ++ks)
            ahi[ks] = *(const short8*)(g + (size_t)l15 * H_ + ks * 32 + 8 * lg);
        __syncthreads();   // ALL waves' loads complete before ANY in-place store
        f32x4 acc[4];
#pragma unroll
        for (int nt = 0; nt < 4; ++nt) acc[nt] = bias[nt];
#pragma unroll
        for (int ks = 0; ks < 8; ++ks) {
#pragma unroll
            for (int nt = 0; nt < 4; ++nt) acc[nt] = MFMA(ahi[ks], bhi[nt][ks], acc[nt]);
#pragma unroll
            for (int nt = 0; nt < 4; ++nt) acc[nt] = MFMA(ahi[ks], blo[nt][ks], acc[nt]);
        }
#pragma unroll
        for (int nt = 0; nt < 4; ++nt)
            *(f32x4*)(slot + (wv * 64 + nt * 16 + l15) * 16 + 4 * lg) = acc[nt];
    }
}

// ---------------------------------------------- recurrence: 512 thr, 8 wv ---
template <bool WRITE_H1, bool FC>
__global__ __launch_bounds__(512, 1) void k_rnn(
    float* __restrict__ buf, const float* __restrict__ Whh,
    const float* __restrict__ Wfc, const float* __restrict__ bfcp,
    float* __restrict__ out)
{
    const int tid = threadIdx.x, lane = tid & 63, wv = tid >> 6;  // wv 0..7
    const int l15 = lane & 15, lg = lane >> 4;
    const int bc = blockIdx.x;

    // each wave owns 32 output cols: n = wv*32 + nt*16 + l15, nt in {0,1}
    short8 bhi[2][8], blo[2][8];
#pragma unroll
    for (int nt = 0; nt < 2; ++nt) {
        const int n = wv * 32 + nt * 16 + l15;
#pragma unroll
        for (int ks = 0; ks < 8; ++ks) {
            const float4* p = (const float4*)(Whh + (size_t)n * H_ + ks * 32 + 8 * lg);
            split8(p[0], p[1], bhi[nt][ks], blo[nt][ks]);
        }
    }
    float wfc2[2];
    float bfc = 0.f;
    if (FC) {
#pragma unroll
        for (int nt = 0; nt < 2; ++nt) wfc2[nt] = Wfc[wv * 32 + nt * 16 + l15];
        bfc = bfcp[0];
    }

    __shared__ unsigned short hb[2][16][264];  // [dbuf][m][k] bf16-HI, +8 pad
    __shared__ float wavesum[2][8][16];

    for (int i = tid; i < (int)(sizeof(hb) / 16); i += 512)
        ((uint4*)hb)[i] = make_uint4(0u, 0u, 0u, 0u);
    __syncthreads();

    float* slot0 = buf + (size_t)bc * T_ * 4096;
    f32x4 cfrag[2];
#pragma unroll
    for (int nt = 0; nt < 2; ++nt)
        cfrag[nt] = *(const f32x4*)(slot0 + (wv * 32 + nt * 16 + l15) * 16 + 4 * lg);

    int p = 0;
#pragma unroll 1
    for (int t = 0; t < T_; ++t) {
        // prefetch t+1's C tile FIRST: step work covers the HBM/L2 latency
        f32x4 cnext[2];
        if (t + 1 < T_) {
#pragma unroll
            for (int nt = 0; nt < 2; ++nt)
                cnext[nt] = *(const f32x4*)(slot0 + (size_t)(t + 1) * 4096 +
                                            (wv * 32 + nt * 16 + l15) * 16 + 4 * lg);
        }
        short8 ahi[8];
#pragma unroll
        for (int ks = 0; ks < 8; ++ks)
            ahi[ks] = *(const short8*)&hb[p][l15][ks * 32 + 8 * lg];
        f32x4 acc[2];
#pragma unroll
        for (int nt = 0; nt < 2; ++nt) acc[nt] = cfrag[nt];
#pragma unroll
        for (int ks = 0; ks < 8; ++ks) {
#pragma unroll
            for (int nt = 0; nt < 2; ++nt) acc[nt] = MFMA(ahi[ks], bhi[nt][ks], acc[nt]);
#pragma unroll
            for (int nt = 0; nt < 2; ++nt) acc[nt] = MFMA(ahi[ks], blo[nt][ks], acc[nt]);
        }
        // epilogue: relu, bf16-hi state update, optional FC partial
        float fcp[4] = {0.f, 0.f, 0.f, 0.f};
#pragma unroll
        for (int nt = 0; nt < 2; ++nt) {
            const int n = wv * 32 + nt * 16 + l15;
#pragma unroll
            for (int j = 0; j < 4; ++j) {
                float v = fmaxf(acc[nt][j], 0.f);
                hb[p ^ 1][4 * lg + j][n] = bf16rne(v);
                if (FC) fcp[j] = fmaf(v, wfc2[nt], fcp[j]);
            }
        }
        if (FC) {
#pragma unroll
            for (int j = 0; j < 4; ++j) {
                float f = fcp[j];
                f += __shfl_xor(f, 1, 64);
                f += __shfl_xor(f, 2, 64);
                f += __shfl_xor(f, 4, 64);
                f += __shfl_xor(f, 8, 64);
                fcp[j] = f;
            }
            if (l15 == 0) {
#pragma unroll
                for (int j = 0; j < 4; ++j) wavesum[p][wv][4 * lg + j] = fcp[j];
            }
        }
        __syncthreads();
        if (WRITE_H1) {  // copy new h (bf16-hi, 8KB) -> global slot(bc,t)
            unsigned short* g = (unsigned short*)(slot0 + (size_t)t * 4096);
            const int rr = tid >> 5, c = (tid & 31) * 8;
            *(uint4*)(g + rr * H_ + c) = *(const uint4*)&hb[p ^ 1][rr][c];
        }
        if (FC) {
            if (wv == 0 && lane < 16) {
                float s = bfc;
#pragma unroll
                for (int w8 = 0; w8 < 8; ++w8) s += wavesum[p][w8][lane];
                out[(size_t)(bc * 16 + lane) * T_ + t] = s;
            }
        }
#pragma unroll
        for (int nt = 0; nt < 2; ++nt) cfrag[nt] = cnext[nt];
        p ^= 1;
    }
}

extern "C" void kernel_launch(void* const* d_in, const int* in_sizes, int n_in,
                              void* d_out, int out_size, void* d_ws, size_t ws_size,
                              hipStream_t stream) {
    (void)in_sizes; (void)n_in; (void)out_size; (void)ws_size;
    const float* x    = (const float*)d_in[0];
    const float* Wih0 = (const float*)d_in[1];
    const float* Whh0 = (const float*)d_in[2];
    const float* bih0 = (const float*)d_in[3];
    const float* bhh0 = (const float*)d_in[4];
    const float* Wih1 = (const float*)d_in[5];
    const float* Whh1 = (const float*)d_in[6];
    const float* bih1 = (const float*)d_in[7];
    const float* bhh1 = (const float*)d_in[8];
    const float* Wfc  = (const float*)d_in[9];
    const float* bfc  = (const float*)d_in[10];

    float* buf = (float*)d_ws;  // 16KB x 16 x 512 slots = 128 MiB
    float* out = (float*)d_out;

    k_gemm0<<<dim3(256), dim3(256), 0, stream>>>(x, Wih0, bih0, bhh0, buf);
    k_rnn<true, false><<<dim3(16), dim3(512), 0, stream>>>(buf, Whh0, Wfc, bfc, out);
    k_gemm1<<<dim3(256), dim3(256), 0, stream>>>(Wih1, bih1, bhh1, buf);
    k_rnn<false, true><<<dim3(16), dim3(512), 0, stream>>>(buf, Whh1, Wfc, bfc, out);
}

// Round 13
// 1409.833 us; speedup vs baseline: 1.3578x; 1.0026x over previous
//
#include <hip/hip_runtime.h>

// RNN_SingleOutput: 2-layer Elman ReLU RNN, B=256 T=512 I=64 H=256, fp32.
// Round-13: attack the ~2900cy/step fixed latency left after R12:
//  (a) LINEAR LDS layout [k>>3][m][k&7]: each wave's 8 ds_read_b128 are
//      contiguous 1KB blocks -> zero read conflicts (R12: 2.1M conflict cy
//      from 528B-stride rows). h1 global slot uses the same layout; the
//      WRITE_H1 copy becomes a straight 16B/thread memcpy; gemm1 reads it.
//  (b) raw s_barrier + lgkmcnt(0)-only drain (asm + sched_barrier fences,
//      rule #18): __syncthreads emitted s_waitcnt vmcnt(0) each step, which
//      drained the C-tile prefetch -> ~450cy exposed HBM/L2 latency. Now the
//      prefetch stays in flight across the barrier.
//  (c) split accumulation: hi-chain (seeded C) + lo-chain (seeded 0) -> two
//      8-deep MFMA chains per nt instead of one 16-deep.
// Numerics unchanged from R12 (validated absmax 2.44e-3 vs 12.3e-3):
// h stored bf16-hi only; W split hi+lo; fp32 accum.
// Pipeline over ONE 128MiB ws buffer of 16KB slots [bc=16][t=512]:
//  1. k_gemm0: slot = pre0T fp32 [256n][16m]
//  2. k_rnn<WRITE_H1>: L0; writes h1 bf16-hi (linear layout, 8KB) in-place
//  3. k_gemm1: h1 -> pre1T fp32 in-place (__syncthreads: needs the vmcnt
//     drain for the in-place read-before-write)
//  4. k_rnn<FC>: L1 + fused FC head -> out

#define T_ 512
#define H_ 256

typedef __attribute__((ext_vector_type(8))) short short8;
typedef __attribute__((ext_vector_type(4))) float f32x4;

#define MFMA(a, b, c) __builtin_amdgcn_mfma_f32_16x16x32_bf16(a, b, c, 0, 0, 0)

__device__ __forceinline__ unsigned short bf16rne(float f) {
    unsigned u = __float_as_uint(f);
    u += 0x7fff + ((u >> 16) & 1);
    return (unsigned short)(u >> 16);
}

__device__ __forceinline__ void split8(const float4 a0, const float4 a1,
                                       short8& hi, short8& lo) {
    const float v[8] = {a0.x, a0.y, a0.z, a0.w, a1.x, a1.y, a1.z, a1.w};
#pragma unroll
    for (int j = 0; j < 8; ++j) {
        unsigned short hb = bf16rne(v[j]);
        float hf = __uint_as_float(((unsigned)hb) << 16);
        unsigned short lb = bf16rne(v[j] - hf);
        hi[j] = (short)hb;
        lo[j] = (short)lb;
    }
}

// LDS-ordering barrier WITHOUT the vmcnt(0) drain __syncthreads emits.
// All call sites are in uniform control flow.
__device__ __forceinline__ void lds_sync() {
    asm volatile("s_waitcnt lgkmcnt(0)" ::: "memory");
    __builtin_amdgcn_sched_barrier(0);
    __builtin_amdgcn_s_barrier();
    __builtin_amdgcn_sched_barrier(0);
    asm volatile("" ::: "memory");
}

// ---------------------------------------------------------- gemm0 (K=64) ---
__global__ __launch_bounds__(256) void k_gemm0(
    const float* __restrict__ x, const float* __restrict__ Wih,
    const float* __restrict__ bih, const float* __restrict__ bhh,
    float* __restrict__ buf)
{
    const int tid = threadIdx.x, lane = tid & 63, wv = tid >> 6;
    const int l15 = lane & 15, lg = lane >> 4;
    const int bc = blockIdx.x & 15;
    const int t0 = (blockIdx.x >> 4) * 32;

    short8 bhi[4][2], blo[4][2];
    f32x4 bias[4];
#pragma unroll
    for (int nt = 0; nt < 4; ++nt) {
        const int n = wv * 64 + nt * 16 + l15;
#pragma unroll
        for (int ks = 0; ks < 2; ++ks) {
            const float4* p = (const float4*)(Wih + (size_t)n * 64 + ks * 32 + 8 * lg);
            split8(p[0], p[1], bhi[nt][ks], blo[nt][ks]);
        }
        const float b = bih[n] + bhh[n];
        bias[nt] = f32x4{b, b, b, b};
    }
#pragma unroll 1
    for (int t = t0; t < t0 + 32; ++t) {
        short8 ahi[2], alo[2];
#pragma unroll
        for (int ks = 0; ks < 2; ++ks) {
            const float4* p =
                (const float4*)(x + ((size_t)(bc * 16 + l15) * T_ + t) * 64 + ks * 32 + 8 * lg);
            split8(p[0], p[1], ahi[ks], alo[ks]);
        }
        f32x4 acc[4];
#pragma unroll
        for (int nt = 0; nt < 4; ++nt) acc[nt] = bias[nt];
#pragma unroll
        for (int ks = 0; ks < 2; ++ks) {
#pragma unroll
            for (int nt = 0; nt < 4; ++nt) acc[nt] = MFMA(ahi[ks], bhi[nt][ks], acc[nt]);
#pragma unroll
            for (int nt = 0; nt < 4; ++nt) acc[nt] = MFMA(alo[ks], bhi[nt][ks], acc[nt]);
#pragma unroll
            for (int nt = 0; nt < 4; ++nt) acc[nt] = MFMA(ahi[ks], blo[nt][ks], acc[nt]);
        }
        float* slot = buf + ((size_t)bc * T_ + t) * 4096;
#pragma unroll
        for (int nt = 0; nt < 4; ++nt)
            *(f32x4*)(slot + (wv * 64 + nt * 16 + l15) * 16 + 4 * lg) = acc[nt];
    }
}

// ------------------------------------- gemm1 (K=256, hi-A, linear layout) ---
__global__ __launch_bounds__(256, 1) void k_gemm1(
    const float* __restrict__ Wih, const float* __restrict__ bih,
    const float* __restrict__ bhh, float* __restrict__ buf)
{
    const int tid = threadIdx.x, lane = tid & 63, wv = tid >> 6;
    const int l15 = lane & 15, lg = lane >> 4;
    const int bc = blockIdx.x & 15;
    const int t0 = (blockIdx.x >> 4) * 32;

    short8 bhi[4][8], blo[4][8];
    f32x4 bias[4];
#pragma unroll
    for (int nt = 0; nt < 4; ++nt) {
        const int n = wv * 64 + nt * 16 + l15;
#pragma unroll
        for (int ks = 0; ks < 8; ++ks) {
            const float4* p = (const float4*)(Wih + (size_t)n * H_ + ks * 32 + 8 * lg);
            split8(p[0], p[1], bhi[nt][ks], blo[nt][ks]);
        }
        const float b = bih[n] + bhh[n];
        bias[nt] = f32x4{b, b, b, b};
    }
#pragma unroll 1
    for (int t = t0; t < t0 + 32; ++t) {
        float* slot = buf + ((size_t)bc * T_ + t) * 4096;
        const unsigned short* g = (const unsigned short*)slot;
        short8 ahi[8];
#pragma unroll
        for (int ks = 0; ks < 8; ++ks)    // linear layout: [k>>3][m][k&7]
            ahi[ks] = *(const short8*)(g + ks * 512 + lg * 128 + l15 * 8);
        __syncthreads();   // full drain: all waves' loads before in-place stores
        f32x4 acc[4];
#pragma unroll
        for (int nt = 0; nt < 4; ++nt) acc[nt] = bias[nt];
#pragma unroll
        for (int ks = 0; ks < 8; ++ks) {
#pragma unroll
            for (int nt = 0; nt < 4; ++nt) acc[nt] = MFMA(ahi[ks], bhi[nt][ks], acc[nt]);
#pragma unroll
            for (int nt = 0; nt < 4; ++nt) acc[nt] = MFMA(ahi[ks], blo[nt][ks], acc[nt]);
        }
#pragma unroll
        for (int nt = 0; nt < 4; ++nt)
            *(f32x4*)(slot + (wv * 64 + nt * 16 + l15) * 16 + 4 * lg) = acc[nt];
    }
}

// ---------------------------------------------- recurrence: 512 thr, 8 wv ---
template <bool WRITE_H1, bool FC>
__global__ __launch_bounds__(512, 1) void k_rnn(
    float* __restrict__ buf, const float* __restrict__ Whh,
    const float* __restrict__ Wfc, const float* __restrict__ bfcp,
    float* __restrict__ out)
{
    const int tid = threadIdx.x, lane = tid & 63, wv = tid >> 6;  // wv 0..7
    const int l15 = lane & 15, lg = lane >> 4;
    const int bc = blockIdx.x;

    // each wave owns 32 output cols: n = wv*32 + nt*16 + l15, nt in {0,1}
    short8 bhi[2][8], blo[2][8];
#pragma unroll
    for (int nt = 0; nt < 2; ++nt) {
        const int n = wv * 32 + nt * 16 + l15;
#pragma unroll
        for (int ks = 0; ks < 8; ++ks) {
            const float4* p = (const float4*)(Whh + (size_t)n * H_ + ks * 32 + 8 * lg);
            split8(p[0], p[1], bhi[nt][ks], blo[nt][ks]);
        }
    }
    float wfc2[2];
    float bfc = 0.f;
    if (FC) {
#pragma unroll
        for (int nt = 0; nt < 2; ++nt) wfc2[nt] = Wfc[wv * 32 + nt * 16 + l15];
        bfc = bfcp[0];
    }

    // h state, LINEAR layout: value(m,n) at short-offset (n>>3)*128 + m*8 + (n&7)
    __shared__ unsigned short hb[2][4096];
    __shared__ float wavesum[2][8][16];

    for (int i = tid; i < 512; ++i == 0 ? i : i)  // (unreachable inc trick avoided)
        ;
    for (int i = tid; i < (int)(sizeof(hb) / 16); i += 512)
        ((uint4*)hb)[i] = make_uint4(0u, 0u, 0u, 0u);
    __syncthreads();

    float* slot0 = buf + (size_t)bc * T_ * 4096;
    f32x4 cfrag[2];
#pragma unroll
    for (int nt = 0; nt < 2; ++nt)
        cfrag[nt] = *(const f32x4*)(slot0 + (wv * 32 + nt * 16 + l15) * 16 + 4 * lg);

    int p = 0;
#pragma unroll 1
    for (int t = 0; t < T_; ++t) {
        // prefetch t+1's C tile; with the raw barrier below it is NOT drained
        // at the barrier and its latency is covered by this whole step.
        f32x4 cnext[2] = {f32x4{0.f, 0.f, 0.f, 0.f}, f32x4{0.f, 0.f, 0.f, 0.f}};
        if (t + 1 < T_) {
#pragma unroll
            for (int nt = 0; nt < 2; ++nt)
                cnext[nt] = *(const f32x4*)(slot0 + (size_t)(t + 1) * 4096 +
                                            (wv * 32 + nt * 16 + l15) * 16 + 4 * lg);
        }
        short8 ahi[8];
#pragma unroll
        for (int ks = 0; ks < 8; ++ks)   // contiguous 1KB per read: 0 conflicts
            ahi[ks] = *(const short8*)&hb[p][ks * 512 + lg * 128 + l15 * 8];
        // split chains: accA (hi products, seeded C) + accB (lo products)
        f32x4 accA[2], accB[2];
#pragma unroll
        for (int nt = 0; nt < 2; ++nt) {
            accA[nt] = cfrag[nt];
            accB[nt] = f32x4{0.f, 0.f, 0.f, 0.f};
        }
#pragma unroll
        for (int ks = 0; ks < 8; ++ks) {
#pragma unroll
            for (int nt = 0; nt < 2; ++nt) accA[nt] = MFMA(ahi[ks], bhi[nt][ks], accA[nt]);
#pragma unroll
            for (int nt = 0; nt < 2; ++nt) accB[nt] = MFMA(ahi[ks], blo[nt][ks], accB[nt]);
        }
        // epilogue: relu, bf16-hi state write (linear layout), FC partial
        float fcp[4] = {0.f, 0.f, 0.f, 0.f};
#pragma unroll
        for (int nt = 0; nt < 2; ++nt) {
            const int gbase = (wv * 4 + nt * 2 + (l15 >> 3)) * 128 + (l15 & 7);
#pragma unroll
            for (int j = 0; j < 4; ++j) {
                float v = fmaxf(accA[nt][j] + accB[nt][j], 0.f);
                hb[p ^ 1][gbase + (4 * lg + j) * 8] = bf16rne(v);
                if (FC) fcp[j] = fmaf(v, wfc2[nt], fcp[j]);
            }
        }
        if (FC) {
#pragma unroll
            for (int j = 0; j < 4; ++j) {
                float f = fcp[j];
                f += __shfl_xor(f, 1, 64);
                f += __shfl_xor(f, 2, 64);
                f += __shfl_xor(f, 4, 64);
                f += __shfl_xor(f, 8, 64);
                fcp[j] = f;
            }
            if (l15 == 0) {
#pragma unroll
                for (int j = 0; j < 4; ++j) wavesum[p][wv][4 * lg + j] = fcp[j];
            }
        }
        lds_sync();   // lgkmcnt(0)+s_barrier only; C prefetch stays in flight
        if (WRITE_H1) {  // straight linear memcpy of the new h (8KB) to slot t
            unsigned short* gst = (unsigned short*)(slot0 + (size_t)t * 4096);
            *(uint4*)(gst + tid * 8) = *(const uint4*)&hb[p ^ 1][tid * 8];
        }
        if (FC) {
            if (wv == 0 && lane < 16) {
                float s = bfc;
#pragma unroll
                for (int w8 = 0; w8 < 8; ++w8) s += wavesum[p][w8][lane];
                out[(size_t)(bc * 16 + lane) * T_ + t] = s;
            }
        }
#pragma unroll
        for (int nt = 0; nt < 2; ++nt) cfrag[nt] = cnext[nt];
        p ^= 1;
    }
}

extern "C" void kernel_launch(void* const* d_in, const int* in_sizes, int n_in,
                              void* d_out, int out_size, void* d_ws, size_t ws_size,
                              hipStream_t stream) {
    (void)in_sizes; (void)n_in; (void)out_size; (void)ws_size;
    const float* x    = (const float*)d_in[0];
    const float* Wih0 = (const float*)d_in[1];
    const float* Whh0 = (const float*)d_in[2];
    const float* bih0 = (const float*)d_in[3];
    const float* bhh0 = (const float*)d_in[4];
    const float* Wih1 = (const float*)d_in[5];
    const float* Whh1 = (const float*)d_in[6];
    const float* bih1 = (const float*)d_in[7];
    const float* bhh1 = (const float*)d_in[8];
    const float* Wfc  = (const float*)d_in[9];
    const float* bfc  = (const float*)d_in[10];

    float* buf = (float*)d_ws;  // 16KB x 16 x 512 slots = 128 MiB
    float* out = (float*)d_out;

    k_gemm0<<<dim3(256), dim3(256), 0, stream>>>(x, Wih0, bih0, bhh0, buf);
    k_rnn<true, false><<<dim3(16), dim3(512), 0, stream>>>(buf, Whh0, Wfc, bfc, out);
    k_gemm1<<<dim3(256), dim3(256), 0, stream>>>(Wih1, bih1, bhh1, buf);
    k_rnn<false, true><<<dim3(16), dim3(512), 0, stream>>>(buf, Whh1, Wfc, bfc, out);
}

// Round 14
// 1369.129 us; speedup vs baseline: 1.3982x; 1.0297x over previous
//
#include <hip/hip_runtime.h>

// RNN_SingleOutput: 2-layer Elman ReLU RNN, B=256 T=512 I=64 H=256, fp32.
// Round-14: CROSS-BLOCK LAYER PIPELINE. R13 proved the ~3380cy/step is an
// irreducible serial chain of the barrier-step structure (conflict fix, vmcnt
// fix, chain split: all ~0). So overlap the two 512-step recurrences instead:
//  48 blocks: [0..15]=L0 (recurrence0 + folded x-projection),
//             [16..31]=G1 (elastic pre1 = Wih1@h1 + b stage),
//             [32..47]=L1 (recurrence1 + FC head).
//  Handoff: ring buffers (depth 32) + per-chunk monotonic step flags with
//  agent-scope release/acquire. Chunk bc's 3 blocks land on one XCD (%8).
//  Steady state: L1 runs ~3 steps behind L0 -> total ~= 516 steps not 1024.
// ws: h1ring 4MiB @0, pre1ring 8MiB @4MiB, flags @12MiB (<=13MiB used).
// Numerics (validated base absmax 2.44e-3): h bf16-hi state, W hi+lo split,
// fp32 accum; NEW: x as bf16-hi (adds ~2e-3 predicted at out).

#define T_ 512
#define H_ 256
#define RD 32

typedef __attribute__((ext_vector_type(8))) short short8;
typedef __attribute__((ext_vector_type(4))) float f32x4;

#define MFMA(a, b, c) __builtin_amdgcn_mfma_f32_16x16x32_bf16(a, b, c, 0, 0, 0)

__device__ __forceinline__ unsigned short bf16rne(float f) {
    unsigned u = __float_as_uint(f);
    u += 0x7fff + ((u >> 16) & 1);
    return (unsigned short)(u >> 16);
}

__device__ __forceinline__ void split8(const float4 a0, const float4 a1,
                                       short8& hi, short8& lo) {
    const float v[8] = {a0.x, a0.y, a0.z, a0.w, a1.x, a1.y, a1.z, a1.w};
#pragma unroll
    for (int j = 0; j < 8; ++j) {
        unsigned short hb = bf16rne(v[j]);
        float hf = __uint_as_float(((unsigned)hb) << 16);
        unsigned short lb = bf16rne(v[j] - hf);
        hi[j] = (short)hb;
        lo[j] = (short)lb;
    }
}

__device__ __forceinline__ int aload(const int* p) {
    return __hip_atomic_load(p, __ATOMIC_ACQUIRE, __HIP_MEMORY_SCOPE_AGENT);
}
__device__ __forceinline__ void astore(int* p, int v) {
    __hip_atomic_store(p, v, __ATOMIC_RELEASE, __HIP_MEMORY_SCOPE_AGENT);
}

__global__ __launch_bounds__(256) void k_init(int* flags) {
    for (int i = threadIdx.x; i < 48 * 64; i += 256) flags[i] = 0;
}

__global__ __launch_bounds__(512, 1) void k_pipe(
    const float* __restrict__ x,
    const float* __restrict__ Wih0, const float* __restrict__ Whh0,
    const float* __restrict__ bih0, const float* __restrict__ bhh0,
    const float* __restrict__ Wih1, const float* __restrict__ Whh1,
    const float* __restrict__ bih1, const float* __restrict__ bhh1,
    const float* __restrict__ Wfc, const float* __restrict__ bfcp,
    float* __restrict__ out, char* __restrict__ ws)
{
    unsigned short* h1ring = (unsigned short*)ws;            // 16*32*8KB = 4MiB
    float* p1ring = (float*)(ws + (4u << 20));               // 16*32*16KB = 8MiB
    int* flags = (int*)(ws + (12u << 20));
    const int role = blockIdx.x >> 4;  // 0=L0 1=G1 2=L1
    const int bc = blockIdx.x & 15;
    int* f01 = flags + bc * 64;          // L0 progress: h1(0..v-1) ready
    int* f12 = flags + (16 + bc) * 64;   // G1 progress: pre1(0..v-1) ready
    int* fl1 = flags + (32 + bc) * 64;   // L1 progress (flow control)

    const int tid = threadIdx.x, lane = tid & 63, wv = tid >> 6;
    const int l15 = lane & 15, lg = lane >> 4;

    __shared__ unsigned short hb[2][4096];  // linear: (n>>3)*128 + m*8 + (n&7)
    __shared__ float wavesum[2][8][16];

    if (role == 0) {
        // ================= L0: recurrence 0 with folded input projection ====
        short8 whi[2][8], wlo[2][8];   // Whh0 split
        short8 uhi[2][2], ulo[2][2];   // Wih0 split (K=64)
        f32x4 bias2[2];
#pragma unroll
        for (int nt = 0; nt < 2; ++nt) {
            const int n = wv * 32 + nt * 16 + l15;
#pragma unroll
            for (int ks = 0; ks < 8; ++ks) {
                const float4* pw = (const float4*)(Whh0 + (size_t)n * H_ + ks * 32 + 8 * lg);
                split8(pw[0], pw[1], whi[nt][ks], wlo[nt][ks]);
            }
#pragma unroll
            for (int ks = 0; ks < 2; ++ks) {
                const float4* pu = (const float4*)(Wih0 + (size_t)n * 64 + ks * 32 + 8 * lg);
                split8(pu[0], pu[1], uhi[nt][ks], ulo[nt][ks]);
            }
            const float b = bih0[n] + bhh0[n];
            bias2[nt] = f32x4{b, b, b, b};
        }
        for (int i = tid; i < 1024; i += 512) ((uint4*)hb)[i] = make_uint4(0u, 0u, 0u, 0u);
        __syncthreads();

        // initial x(0) frags (bf16-hi)
        short8 xcur[2];
        {
            const float* xrow = x + ((size_t)(bc * 16 + l15) * T_) * 64;
#pragma unroll
            for (int ks = 0; ks < 2; ++ks) {
                const float4* p4 = (const float4*)(xrow + ks * 32 + 8 * lg);
                float4 a0 = p4[0], a1 = p4[1];
                const float v[8] = {a0.x, a0.y, a0.z, a0.w, a1.x, a1.y, a1.z, a1.w};
#pragma unroll
                for (int j = 0; j < 8; ++j) xcur[ks][j] = (short)bf16rne(v[j]);
            }
        }
        int pp = 0;
#pragma unroll 1
        for (int t = 0; t < T_; ++t) {
            __syncthreads();  // A: drains prev step's ring-copy stores (all threads)
            if (tid == 0) {
                if (t > 0) astore(f01, t);                       // h1(0..t-1) ready
                if (t >= RD) { while (aload(f12) < t - RD + 1) {} }  // slot reuse
            }
            __syncthreads();  // A2
            short8 xnext[2] = {xcur[0], xcur[1]};
            if (t + 1 < T_) {
                const float* xrow = x + ((size_t)(bc * 16 + l15) * T_ + (t + 1)) * 64;
#pragma unroll
                for (int ks = 0; ks < 2; ++ks) {
                    const float4* p4 = (const float4*)(xrow + ks * 32 + 8 * lg);
                    float4 a0 = p4[0], a1 = p4[1];
                    const float v[8] = {a0.x, a0.y, a0.z, a0.w, a1.x, a1.y, a1.z, a1.w};
#pragma unroll
                    for (int j = 0; j < 8; ++j) xnext[ks][j] = (short)bf16rne(v[j]);
                }
            }
            short8 ahi[8];
#pragma unroll
            for (int ks = 0; ks < 8; ++ks)
                ahi[ks] = *(const short8*)&hb[pp][ks * 512 + lg * 128 + l15 * 8];
            f32x4 accA[2], accB[2];
#pragma unroll
            for (int nt = 0; nt < 2; ++nt) { accA[nt] = bias2[nt]; accB[nt] = f32x4{0.f, 0.f, 0.f, 0.f}; }
#pragma unroll
            for (int ks = 0; ks < 8; ++ks) {
#pragma unroll
                for (int nt = 0; nt < 2; ++nt) accA[nt] = MFMA(ahi[ks], whi[nt][ks], accA[nt]);
#pragma unroll
                for (int nt = 0; nt < 2; ++nt) accB[nt] = MFMA(ahi[ks], wlo[nt][ks], accB[nt]);
            }
#pragma unroll
            for (int ks = 0; ks < 2; ++ks) {
#pragma unroll
                for (int nt = 0; nt < 2; ++nt) accA[nt] = MFMA(xcur[ks], uhi[nt][ks], accA[nt]);
#pragma unroll
                for (int nt = 0; nt < 2; ++nt) accB[nt] = MFMA(xcur[ks], ulo[nt][ks], accB[nt]);
            }
#pragma unroll
            for (int nt = 0; nt < 2; ++nt) {
                const int gbase = (wv * 4 + nt * 2 + (l15 >> 3)) * 128 + (l15 & 7);
#pragma unroll
                for (int j = 0; j < 4; ++j) {
                    float v = fmaxf(accA[nt][j] + accB[nt][j], 0.f);
                    hb[pp ^ 1][gbase + (4 * lg + j) * 8] = bf16rne(v);
                }
            }
            __syncthreads();  // B: hb[pp^1] complete
            {
                unsigned short* g = h1ring + ((size_t)bc * RD + (t & (RD - 1))) * 4096;
                *(uint4*)(g + tid * 8) = *(const uint4*)&hb[pp ^ 1][tid * 8];
            }
            xcur[0] = xnext[0]; xcur[1] = xnext[1];
            pp ^= 1;
        }
        __syncthreads();
        if (tid == 0) astore(f01, T_);
    } else if (role == 1) {
        // ================= G1: elastic projection pre1(t) = Wih1@h1(t)+b ====
        short8 whi[2][8], wlo[2][8];
        f32x4 bias2[2];
#pragma unroll
        for (int nt = 0; nt < 2; ++nt) {
            const int n = wv * 32 + nt * 16 + l15;
#pragma unroll
            for (int ks = 0; ks < 8; ++ks) {
                const float4* pw = (const float4*)(Wih1 + (size_t)n * H_ + ks * 32 + 8 * lg);
                split8(pw[0], pw[1], whi[nt][ks], wlo[nt][ks]);
            }
            const float b = bih1[n] + bhh1[n];
            bias2[nt] = f32x4{b, b, b, b};
        }
#pragma unroll 1
        for (int t = 0; t < T_; ++t) {
            if (tid == 0) {
                while (aload(f01) < t + 1) {}
                if (t >= RD) { while (aload(fl1) < t - RD + 1) {} }
            }
            __syncthreads();
            const unsigned short* g = h1ring + ((size_t)bc * RD + (t & (RD - 1))) * 4096;
            short8 ahi[8];
#pragma unroll
            for (int ks = 0; ks < 8; ++ks)
                ahi[ks] = *(const short8*)(g + ks * 512 + lg * 128 + l15 * 8);
            f32x4 accA[2], accB[2];
#pragma unroll
            for (int nt = 0; nt < 2; ++nt) { accA[nt] = bias2[nt]; accB[nt] = f32x4{0.f, 0.f, 0.f, 0.f}; }
#pragma unroll
            for (int ks = 0; ks < 8; ++ks) {
#pragma unroll
                for (int nt = 0; nt < 2; ++nt) accA[nt] = MFMA(ahi[ks], whi[nt][ks], accA[nt]);
#pragma unroll
                for (int nt = 0; nt < 2; ++nt) accB[nt] = MFMA(ahi[ks], wlo[nt][ks], accB[nt]);
            }
            float* dst = p1ring + ((size_t)bc * RD + (t & (RD - 1))) * 4096;
#pragma unroll
            for (int nt = 0; nt < 2; ++nt) {
                const int n = wv * 32 + nt * 16 + l15;
                f32x4 v;
#pragma unroll
                for (int j = 0; j < 4; ++j) v[j] = accA[nt][j] + accB[nt][j];
                *(f32x4*)(dst + n * 16 + 4 * lg) = v;
            }
            __syncthreads();  // drains pre1 stores (vmcnt0) before publish
            if (tid == 0) astore(f12, t + 1);
        }
    } else {
        // ================= L1: recurrence 1 + FC head =======================
        short8 whi[2][8], wlo[2][8];
#pragma unroll
        for (int nt = 0; nt < 2; ++nt) {
            const int n = wv * 32 + nt * 16 + l15;
#pragma unroll
            for (int ks = 0; ks < 8; ++ks) {
                const float4* pw = (const float4*)(Whh1 + (size_t)n * H_ + ks * 32 + 8 * lg);
                split8(pw[0], pw[1], whi[nt][ks], wlo[nt][ks]);
            }
        }
        float wfc2[2];
#pragma unroll
        for (int nt = 0; nt < 2; ++nt) wfc2[nt] = Wfc[wv * 32 + nt * 16 + l15];
        const float bfc = bfcp[0];
        for (int i = tid; i < 1024; i += 512) ((uint4*)hb)[i] = make_uint4(0u, 0u, 0u, 0u);
        __syncthreads();

        if (tid == 0) { while (aload(f12) < 1) {} }
        __syncthreads();
        f32x4 cfrag[2];
        {
            const float* src = p1ring + (size_t)bc * RD * 4096;
#pragma unroll
            for (int nt = 0; nt < 2; ++nt)
                cfrag[nt] = *(const f32x4*)(src + (wv * 32 + nt * 16 + l15) * 16 + 4 * lg);
        }
        int pp = 0;
#pragma unroll 1
        for (int t = 0; t < T_; ++t) {
            __syncthreads();  // A
            if (tid == 0) {
                astore(fl1, t);
                if (t + 1 < T_) { while (aload(f12) < t + 2) {} }
            }
            __syncthreads();  // A2
            f32x4 cnext[2] = {cfrag[0], cfrag[1]};
            if (t + 1 < T_) {
                const float* src = p1ring + ((size_t)bc * RD + ((t + 1) & (RD - 1))) * 4096;
#pragma unroll
                for (int nt = 0; nt < 2; ++nt)
                    cnext[nt] = *(const f32x4*)(src + (wv * 32 + nt * 16 + l15) * 16 + 4 * lg);
            }
            short8 ahi[8];
#pragma unroll
            for (int ks = 0; ks < 8; ++ks)
                ahi[ks] = *(const short8*)&hb[pp][ks * 512 + lg * 128 + l15 * 8];
            f32x4 accA[2], accB[2];
#pragma unroll
            for (int nt = 0; nt < 2; ++nt) { accA[nt] = cfrag[nt]; accB[nt] = f32x4{0.f, 0.f, 0.f, 0.f}; }
#pragma unroll
            for (int ks = 0; ks < 8; ++ks) {
#pragma unroll
                for (int nt = 0; nt < 2; ++nt) accA[nt] = MFMA(ahi[ks], whi[nt][ks], accA[nt]);
#pragma unroll
                for (int nt = 0; nt < 2; ++nt) accB[nt] = MFMA(ahi[ks], wlo[nt][ks], accB[nt]);
            }
            float fcp[4] = {0.f, 0.f, 0.f, 0.f};
#pragma unroll
            for (int nt = 0; nt < 2; ++nt) {
                const int gbase = (wv * 4 + nt * 2 + (l15 >> 3)) * 128 + (l15 & 7);
#pragma unroll
                for (int j = 0; j < 4; ++j) {
                    float v = fmaxf(accA[nt][j] + accB[nt][j], 0.f);
                    hb[pp ^ 1][gbase + (4 * lg + j) * 8] = bf16rne(v);
                    fcp[j] = fmaf(v, wfc2[nt], fcp[j]);
                }
            }
#pragma unroll
            for (int j = 0; j < 4; ++j) {
                float f = fcp[j];
                f += __shfl_xor(f, 1, 64);
                f += __shfl_xor(f, 2, 64);
                f += __shfl_xor(f, 4, 64);
                f += __shfl_xor(f, 8, 64);
                fcp[j] = f;
            }
            if (l15 == 0) {
#pragma unroll
                for (int j = 0; j < 4; ++j) wavesum[pp][wv][4 * lg + j] = fcp[j];
            }
            __syncthreads();  // B
            if (wv == 0 && lane < 16) {
                float s = bfc;
#pragma unroll
                for (int w8 = 0; w8 < 8; ++w8) s += wavesum[pp][w8][lane];
                out[(size_t)(bc * 16 + lane) * T_ + t] = s;
            }
            cfrag[0] = cnext[0]; cfrag[1] = cnext[1];
            pp ^= 1;
        }
    }
}

extern "C" void kernel_launch(void* const* d_in, const int* in_sizes, int n_in,
                              void* d_out, int out_size, void* d_ws, size_t ws_size,
                              hipStream_t stream) {
    (void)in_sizes; (void)n_in; (void)out_size; (void)ws_size;
    const float* x    = (const float*)d_in[0];
    const float* Wih0 = (const float*)d_in[1];
    const float* Whh0 = (const float*)d_in[2];
    const float* bih0 = (const float*)d_in[3];
    const float* bhh0 = (const float*)d_in[4];
    const float* Wih1 = (const float*)d_in[5];
    const float* Whh1 = (const float*)d_in[6];
    const float* bih1 = (const float*)d_in[7];
    const float* bhh1 = (const float*)d_in[8];
    const float* Wfc  = (const float*)d_in[9];
    const float* bfc  = (const float*)d_in[10];

    char* ws  = (char*)d_ws;                      // uses 12MiB + 12KB
    int* flags = (int*)(ws + (12u << 20));
    float* out = (float*)d_out;

    k_init<<<dim3(1), dim3(256), 0, stream>>>(flags);
    k_pipe<<<dim3(48), dim3(512), 0, stream>>>(
        x, Wih0, Whh0, bih0, bhh0, Wih1, Whh1, bih1, bhh1, Wfc, bfc, out, ws);
}